// Round 3
// baseline (1155.499 us; speedup 1.0000x reference)
//
#include <hip/hip_runtime.h>
#include <stdint.h>

#define BB 1024
#define SS 512
#define HH 128
#define GG 384
#define MM 16
#define BLK 512
#define NBLK (BB / MM)   // 64 blocks
#define GHS 17           // gh stride in floats (odd -> conflict-free scalar access)
#define HBS 136          // h f16 row stride in shorts (136*2B = 272B = 16B-aligned rows)

typedef float f32x4 __attribute__((ext_vector_type(4)));
typedef _Float16 f16x8 __attribute__((ext_vector_type(8)));

#define LO_SCALE 2048.0f
#define LO_INV   (1.0f / 2048.0f)

__device__ __forceinline__ float sigf(float x) { return 1.0f / (1.0f + __expf(-x)); }
__device__ __forceinline__ float tanh_fast(float x) { return 2.0f / (1.0f + __expf(-2.0f * x)) - 1.0f; }

__global__ __launch_bounds__(BLK, 2) void pig_kernel(
    const float* __restrict__ x0, const float* __restrict__ v_seq,
    const float* __restrict__ W_ih, const float* __restrict__ W_hh,
    const float* __restrict__ b_ih, const float* __restrict__ b_hh,
    const float* __restrict__ W_out, const float* __restrict__ b_out,
    const float* __restrict__ W_r1, const float* __restrict__ b_r1,
    const float* __restrict__ W_r2, const float* __restrict__ b_r2,
    float* __restrict__ out)
{
    __shared__ __align__(16) float     gh[GG * GHS];     // raw h@W_hh^T, [gate][m]
    __shared__ __align__(16) _Float16  hh16[MM * HBS];   // h high part (f16)
    __shared__ __align__(16) _Float16  hl16[MM * HBS];   // h low part  (f16, x2048)
    __shared__ __align__(16) float     hf[MM * HH];      // h in fp32
    __shared__ __align__(16) float     hid[MM * 64];     // residual-MLP hidden
    __shared__ float xprev[MM * 2];
    __shared__ float vbuf[2][MM * 2];

    const int tid  = threadIdx.x;
    const int wave = tid >> 6;
    const int lane = tid & 63;
    const int quad = lane >> 4;
    const int col  = lane & 15;
    const int row0 = blockIdx.x * MM;

    // ---- W_hh B-fragments (f16 hi + scaled lo), resident in VGPRs all 512 steps ----
    // B[k][n] = W_hh[n][k]; lane holds n = col, k = kk*32 + quad*8 + i
    f16x8 whi[3][4], wlo[3][4];
#pragma unroll
    for (int nt = 0; nt < 3; ++nt) {
        const int g = wave * 48 + nt * 16 + col;
#pragma unroll
        for (int kk = 0; kk < 4; ++kk) {
            const float* p = W_hh + g * HH + kk * 32 + quad * 8;
            f16x8 fh, fl;
#pragma unroll
            for (int i = 0; i < 8; ++i) {
                float w = p[i];
                _Float16 h = (_Float16)w;
                fh[i] = h;
                fl[i] = (_Float16)((w - (float)h) * LO_SCALE);
            }
            whi[nt][kk] = fh;
            wlo[nt][kk] = fl;
        }
    }

    // ---- phase-B (h update) per-thread constants ----
    const int j  = tid & 127;
    const int mq = tid >> 7;   // handles m = mq*4 .. mq*4+3
    const float wr0 = W_ih[j*2],        wr1 = W_ih[j*2+1];
    const float wz0 = W_ih[(HH+j)*2],   wz1 = W_ih[(HH+j)*2+1];
    const float wn0 = W_ih[(2*HH+j)*2], wn1 = W_ih[(2*HH+j)*2+1];
    const float br  = b_ih[j]      + b_hh[j];
    const float bz  = b_ih[HH+j]   + b_hh[HH+j];
    const float bni = b_ih[2*HH+j];
    const float bnh = b_hh[2*HH+j];

    // ---- C1 (residual hidden) per-thread constants ----
    const int mC = tid >> 5;          // 0..15
    const int k0 = (tid & 31) * 2;    // two hidden units
    const float a00 = W_r1[k0*4],     a01 = W_r1[k0*4+1],     a02 = W_r1[k0*4+2],     a03 = W_r1[k0*4+3];
    const float a10 = W_r1[(k0+1)*4], a11 = W_r1[(k0+1)*4+1], a12 = W_r1[(k0+1)*4+2], a13 = W_r1[(k0+1)*4+3];
    const float ab0 = b_r1[k0], ab1 = b_r1[k0+1];

    // ---- C2 (outputs) per-thread constants ----
    const int oC = (tid >> 4) & 1;
    const int lC = tid & 15;
    float wo[8], w2[4];
#pragma unroll
    for (int i = 0; i < 8; ++i) wo[i] = W_out[oC*HH + lC*8 + i];
#pragma unroll
    for (int i = 0; i < 4; ++i) w2[i] = W_r2[oC*64 + lC*4 + i];
    const float bo = b_out[oC], b2 = b_r2[oC];

    // ---- init ----
    for (int idx = tid; idx < MM*HH; idx += BLK) {
        hf[idx] = 0.0f;
        hh16[(idx >> 7) * HBS + (idx & 127)] = (_Float16)0.0f;
        hl16[(idx >> 7) * HBS + (idx & 127)] = (_Float16)0.0f;
    }
    if (tid < MM*2) {
        xprev[tid]   = x0[(size_t)(row0 + (tid >> 1)) * 2 + (tid & 1)];
        vbuf[0][tid] = v_seq[((size_t)(row0 + (tid >> 1)) * SS) * 2 + (tid & 1)];
    }

    float vpre = 0.0f;
    for (int t = 0; t <= SS; ++t) {
        __syncthreads();
        // ================= region A =================
        if (t < SS) {
            if (tid < 32 && (t + 1) < SS)
                vpre = v_seq[((size_t)(row0 + (tid >> 1)) * SS + (t + 1)) * 2 + (tid & 1)];
            f32x4 aM0 = {0,0,0,0}, aM1 = {0,0,0,0}, aM2 = {0,0,0,0};
            f32x4 aC0 = {0,0,0,0}, aC1 = {0,0,0,0}, aC2 = {0,0,0,0};
#pragma unroll
            for (int kk = 0; kk < 4; ++kk) {
                f16x8 ah = *(const f16x8*)&hh16[col * HBS + kk * 32 + quad * 8];
                f16x8 al = *(const f16x8*)&hl16[col * HBS + kk * 32 + quad * 8];
                aM0 = __builtin_amdgcn_mfma_f32_16x16x32_f16(ah, whi[0][kk], aM0, 0, 0, 0);
                aM1 = __builtin_amdgcn_mfma_f32_16x16x32_f16(ah, whi[1][kk], aM1, 0, 0, 0);
                aM2 = __builtin_amdgcn_mfma_f32_16x16x32_f16(ah, whi[2][kk], aM2, 0, 0, 0);
                aC0 = __builtin_amdgcn_mfma_f32_16x16x32_f16(al, whi[0][kk], aC0, 0, 0, 0);
                aC1 = __builtin_amdgcn_mfma_f32_16x16x32_f16(al, whi[1][kk], aC1, 0, 0, 0);
                aC2 = __builtin_amdgcn_mfma_f32_16x16x32_f16(al, whi[2][kk], aC2, 0, 0, 0);
                aC0 = __builtin_amdgcn_mfma_f32_16x16x32_f16(ah, wlo[0][kk], aC0, 0, 0, 0);
                aC1 = __builtin_amdgcn_mfma_f32_16x16x32_f16(ah, wlo[1][kk], aC1, 0, 0, 0);
                aC2 = __builtin_amdgcn_mfma_f32_16x16x32_f16(ah, wlo[2][kk], aC2, 0, 0, 0);
            }
            // C layout: col = gate-within-tile, rows = quad*4+i
            const int r0q = quad * 4;
#pragma unroll
            for (int i = 0; i < 4; ++i) {
                gh[(wave*48      + col) * GHS + r0q + i] = aM0[i] + aC0[i] * LO_INV;
                gh[(wave*48 + 16 + col) * GHS + r0q + i] = aM1[i] + aC1[i] * LO_INV;
                gh[(wave*48 + 32 + col) * GHS + r0q + i] = aM2[i] + aC2[i] * LO_INV;
            }
        }
        if (t > 0) {  // C2: outputs for step t-1
            const int tt = t - 1;
            f32x4 hv0 = *(const f32x4*)&hf[mC*HH + lC*8];
            f32x4 hv1 = *(const f32x4*)&hf[mC*HH + lC*8 + 4];
            f32x4 hdv = *(const f32x4*)&hid[mC*64 + lC*4];
            float xps = wo[0]*hv0[0] + wo[1]*hv0[1] + wo[2]*hv0[2] + wo[3]*hv0[3]
                      + wo[4]*hv1[0] + wo[5]*hv1[1] + wo[6]*hv1[2] + wo[7]*hv1[3];
            float rss = w2[0]*hdv[0] + w2[1]*hdv[1] + w2[2]*hdv[2] + w2[3]*hdv[3];
#pragma unroll
            for (int s = 8; s >= 1; s >>= 1) {
                xps += __shfl_xor(xps, s, 64);
                rss += __shfl_xor(rss, s, 64);
            }
            if (lC == 0) {
                float xpred = xps + bo;
                float resid = rss + b2;
                float xpv   = xprev[mC*2 + oC];
                float vv    = vbuf[tt & 1][mC*2 + oC];
                float viol  = xpred - (xpv + vv + resid);
                size_t base = ((size_t)(row0 + mC) * SS + tt) * 2 + oC;
                out[base] = xpred;                          // fp32 output
                out[(size_t)BB * SS * 2 + base] = viol;     // fp32 output
                xprev[mC*2 + oC] = xpred;   // becomes x_prev for step t
            }
        }
        __syncthreads();
        // ================= region B =================
        if (t < SS) {
            if (tid < 32 && (t + 1) < SS) vbuf[(t + 1) & 1][tid] = vpre;
            const float* vb = vbuf[t & 1];
#pragma unroll
            for (int i = 0; i < 4; ++i) {
                const int m = mq * 4 + i;
                const float v0 = vb[m*2], v1 = vb[m*2+1];
                const float gr = gh[(j)        * GHS + m];
                const float gz = gh[(HH + j)   * GHS + m];
                const float gn = gh[(2*HH + j) * GHS + m];
                const float r = sigf(gr + v0*wr0 + v1*wr1 + br);
                const float z = sigf(gz + v0*wz0 + v1*wz1 + bz);
                const float n = tanh_fast(v0*wn0 + v1*wn1 + bni + r * (gn + bnh));
                const float hold = hf[m*HH + j];
                const float hnew = n + z * (hold - n);
                hf[m*HH + j]    = hnew;
                _Float16 hh = (_Float16)hnew;
                hh16[m*HBS + j] = hh;
                hl16[m*HBS + j] = (_Float16)((hnew - (float)hh) * LO_SCALE);
            }
            // C1: residual-MLP hidden for step t
            {
                const float xp0 = xprev[mC*2], xp1 = xprev[mC*2+1];
                const float v0 = vb[mC*2], v1 = vb[mC*2+1];
                float h0 = ab0 + a00*xp0 + a01*xp1 + a02*v0 + a03*v1;
                float h1 = ab1 + a10*xp0 + a11*xp1 + a12*v0 + a13*v1;
                hid[mC*64 + k0]     = fmaxf(h0, 0.0f);
                hid[mC*64 + k0 + 1] = fmaxf(h1, 0.0f);
            }
        }
    }
}

extern "C" void kernel_launch(void* const* d_in, const int* in_sizes, int n_in,
                              void* d_out, int out_size, void* d_ws, size_t ws_size,
                              hipStream_t stream) {
    pig_kernel<<<dim3(NBLK), dim3(BLK), 0, stream>>>(
        (const float*)d_in[0],  (const float*)d_in[1],  (const float*)d_in[2],
        (const float*)d_in[3],  (const float*)d_in[4],  (const float*)d_in[5],
        (const float*)d_in[6],  (const float*)d_in[7],  (const float*)d_in[8],
        (const float*)d_in[9],  (const float*)d_in[10], (const float*)d_in[11],
        (float*)d_out);
}

// Round 4
// 781.328 us; speedup vs baseline: 1.4789x; 1.4789x over previous
//
#include <hip/hip_runtime.h>
#include <stdint.h>

#define BB 1024
#define SS 512
#define HH 128
#define GG 384
#define MM 4            // batch rows per block
#define BLK 512
#define NBLK (BB / MM)  // 256 blocks -> 1 per CU
#define GHS 13          // gh stride in floats: reads (13j) and writes (13c+4q) both 2-way max -> free
#define HBS 136         // h f16 row stride in shorts (272B rows, 16B-aligned; b128 reads at 8/bank uniform)

typedef float f32x4 __attribute__((ext_vector_type(4)));
typedef _Float16 f16x8 __attribute__((ext_vector_type(8)));

#define LO_SCALE 2048.0f
#define LO_INV   (1.0f / 2048.0f)

__device__ __forceinline__ float sigf(float x) { return 1.0f / (1.0f + __expf(-x)); }
__device__ __forceinline__ float tanh_fast(float x) { return 2.0f / (1.0f + __expf(-2.0f * x)) - 1.0f; }

__global__ __launch_bounds__(BLK, 2) void pig_kernel(
    const float* __restrict__ x0, const float* __restrict__ v_seq,
    const float* __restrict__ W_ih, const float* __restrict__ W_hh,
    const float* __restrict__ b_ih, const float* __restrict__ b_hh,
    const float* __restrict__ W_out, const float* __restrict__ b_out,
    const float* __restrict__ W_r1, const float* __restrict__ b_r1,
    const float* __restrict__ W_r2, const float* __restrict__ b_r2,
    float* __restrict__ out)
{
    __shared__ __align__(16) float     gh[GG * GHS];     // raw h@W_hh^T, [gate][m]
    __shared__ __align__(16) _Float16  hh16[16 * HBS];   // h high part (f16); rows MM..15 stay zero
    __shared__ __align__(16) _Float16  hl16[16 * HBS];   // h low part  (f16, x2048)
    __shared__ __align__(16) float     hf[MM * HH];      // h in fp32 (for output head)
    __shared__ __align__(16) float     hid[MM * 64];     // residual-MLP hidden
    __shared__ float xprev[MM * 2];
    __shared__ float vbuf[2][MM * 2];

    const int tid  = threadIdx.x;
    const int wave = tid >> 6;
    const int lane = tid & 63;
    const int quad = lane >> 4;
    const int col  = lane & 15;
    const int row0 = blockIdx.x * MM;

    // ---- W_hh B-fragments (f16 hi + scaled lo), resident in VGPRs all 512 steps ----
    // B[k][n] = W_hh[n][k]; lane holds n = col, k = kk*32 + quad*8 + i
    f16x8 whi[3][4], wlo[3][4];
#pragma unroll
    for (int nt = 0; nt < 3; ++nt) {
        const int g = wave * 48 + nt * 16 + col;
#pragma unroll
        for (int kk = 0; kk < 4; ++kk) {
            const float* p = W_hh + g * HH + kk * 32 + quad * 8;
            f16x8 fh, fl;
#pragma unroll
            for (int i = 0; i < 8; ++i) {
                float w = p[i];
                _Float16 h = (_Float16)w;
                fh[i] = h;
                fl[i] = (_Float16)((w - (float)h) * LO_SCALE);
            }
            whi[nt][kk] = fh;
            wlo[nt][kk] = fl;
        }
    }

    // ---- phase-B (h update) per-thread constants: one (m, j) unit per thread ----
    const int j  = tid & 127;
    const int mB = tid >> 7;   // 0..3
    const float wr0 = W_ih[j*2],        wr1 = W_ih[j*2+1];
    const float wz0 = W_ih[(HH+j)*2],   wz1 = W_ih[(HH+j)*2+1];
    const float wn0 = W_ih[(2*HH+j)*2], wn1 = W_ih[(2*HH+j)*2+1];
    const float br  = b_ih[j]      + b_hh[j];
    const float bz  = b_ih[HH+j]   + b_hh[HH+j];
    const float bni = b_ih[2*HH+j];
    const float bnh = b_hh[2*HH+j];

    // ---- C1 (residual hidden) per-thread constants: one (m, k) unit, tid<256 active ----
    const int m1 = tid >> 6;          // 0..7 (only 0..3 used)
    const int k1 = tid & 63;
    const float a0 = W_r1[k1*4], a1 = W_r1[k1*4+1], a2 = W_r1[k1*4+2], a3 = W_r1[k1*4+3];
    const float ab = b_r1[k1];

    // ---- C2 (outputs) per-thread constants: tid<128 active, group = (mC, oC) x 16 lanes ----
    const int mC = tid >> 5;          // 0..3 for tid<128
    const int oC = (tid >> 4) & 1;
    const int lC = tid & 15;
    float wo[8], w2[4];
#pragma unroll
    for (int i = 0; i < 8; ++i) wo[i] = W_out[oC*HH + lC*8 + i];
#pragma unroll
    for (int i = 0; i < 4; ++i) w2[i] = W_r2[oC*64 + lC*4 + i];
    const float bo = b_out[oC], b2 = b_r2[oC];

    // ---- init ----
    hf[tid & 511] = 0.0f;                       // MM*HH == 512 == BLK
    for (int idx = tid; idx < 16 * HBS; idx += BLK) {
        hh16[idx] = (_Float16)0.0f;
        hl16[idx] = (_Float16)0.0f;
    }
    if (tid < MM*2) {
        xprev[tid]   = x0[(size_t)(row0 + (tid >> 1)) * 2 + (tid & 1)];
        vbuf[0][tid] = v_seq[((size_t)(row0 + (tid >> 1)) * SS) * 2 + (tid & 1)];
    }

    float vpre = 0.0f;
    for (int t = 0; t <= SS; ++t) {
        __syncthreads();
        // ================= region A =================
        if (t < SS) {
            if (tid < MM*2 && (t + 1) < SS)
                vpre = v_seq[((size_t)(row0 + (tid >> 1)) * SS + (t + 1)) * 2 + (tid & 1)];
            f32x4 aM0 = {0,0,0,0}, aM1 = {0,0,0,0}, aM2 = {0,0,0,0};
            f32x4 aC0 = {0,0,0,0}, aC1 = {0,0,0,0}, aC2 = {0,0,0,0};
#pragma unroll
            for (int kk = 0; kk < 4; ++kk) {
                f16x8 ah = *(const f16x8*)&hh16[col * HBS + kk * 32 + quad * 8];
                f16x8 al = *(const f16x8*)&hl16[col * HBS + kk * 32 + quad * 8];
                aM0 = __builtin_amdgcn_mfma_f32_16x16x32_f16(ah, whi[0][kk], aM0, 0, 0, 0);
                aM1 = __builtin_amdgcn_mfma_f32_16x16x32_f16(ah, whi[1][kk], aM1, 0, 0, 0);
                aM2 = __builtin_amdgcn_mfma_f32_16x16x32_f16(ah, whi[2][kk], aM2, 0, 0, 0);
                aC0 = __builtin_amdgcn_mfma_f32_16x16x32_f16(al, whi[0][kk], aC0, 0, 0, 0);
                aC1 = __builtin_amdgcn_mfma_f32_16x16x32_f16(al, whi[1][kk], aC1, 0, 0, 0);
                aC2 = __builtin_amdgcn_mfma_f32_16x16x32_f16(al, whi[2][kk], aC2, 0, 0, 0);
                aC0 = __builtin_amdgcn_mfma_f32_16x16x32_f16(ah, wlo[0][kk], aC0, 0, 0, 0);
                aC1 = __builtin_amdgcn_mfma_f32_16x16x32_f16(ah, wlo[1][kk], aC1, 0, 0, 0);
                aC2 = __builtin_amdgcn_mfma_f32_16x16x32_f16(ah, wlo[2][kk], aC2, 0, 0, 0);
            }
            // C layout: col = gate-within-tile, rows = quad*4+i (only rows 0..3 meaningful)
            const int r0q = quad * 4;
#pragma unroll
            for (int i = 0; i < 4; ++i) {
                gh[(wave*48      + col) * GHS + r0q + i] = aM0[i] + aC0[i] * LO_INV;
                gh[(wave*48 + 16 + col) * GHS + r0q + i] = aM1[i] + aC1[i] * LO_INV;
                gh[(wave*48 + 32 + col) * GHS + r0q + i] = aM2[i] + aC2[i] * LO_INV;
            }
        }
        if (t > 0 && tid < 128) {  // C2: outputs for step t-1 (waves 0-1 only)
            const int tt = t - 1;
            f32x4 hv0 = *(const f32x4*)&hf[mC*HH + lC*8];
            f32x4 hv1 = *(const f32x4*)&hf[mC*HH + lC*8 + 4];
            f32x4 hdv = *(const f32x4*)&hid[mC*64 + lC*4];
            float xps = wo[0]*hv0[0] + wo[1]*hv0[1] + wo[2]*hv0[2] + wo[3]*hv0[3]
                      + wo[4]*hv1[0] + wo[5]*hv1[1] + wo[6]*hv1[2] + wo[7]*hv1[3];
            float rss = w2[0]*hdv[0] + w2[1]*hdv[1] + w2[2]*hdv[2] + w2[3]*hdv[3];
#pragma unroll
            for (int s = 8; s >= 1; s >>= 1) {
                xps += __shfl_xor(xps, s, 64);
                rss += __shfl_xor(rss, s, 64);
            }
            if (lC == 0) {
                float xpred = xps + bo;
                float resid = rss + b2;
                float xpv   = xprev[mC*2 + oC];
                float vv    = vbuf[tt & 1][mC*2 + oC];
                float viol  = xpred - (xpv + vv + resid);
                size_t base = ((size_t)(row0 + mC) * SS + tt) * 2 + oC;
                out[base] = xpred;
                out[(size_t)BB * SS * 2 + base] = viol;
                xprev[mC*2 + oC] = xpred;   // becomes x_prev for step t
            }
        }
        __syncthreads();
        // ================= region B =================
        if (t < SS) {
            if (tid < MM*2 && (t + 1) < SS) vbuf[(t + 1) & 1][tid] = vpre;
            const float* vb = vbuf[t & 1];
            {
                const float v0 = vb[mB*2], v1 = vb[mB*2+1];
                const float gr = gh[(j)        * GHS + mB];
                const float gz = gh[(HH + j)   * GHS + mB];
                const float gn = gh[(2*HH + j) * GHS + mB];
                const float r = sigf(gr + v0*wr0 + v1*wr1 + br);
                const float z = sigf(gz + v0*wz0 + v1*wz1 + bz);
                const float n = tanh_fast(v0*wn0 + v1*wn1 + bni + r * (gn + bnh));
                const float hold = hf[mB*HH + j];
                const float hnew = n + z * (hold - n);
                hf[mB*HH + j]    = hnew;
                _Float16 hh = (_Float16)hnew;
                hh16[mB*HBS + j] = hh;
                hl16[mB*HBS + j] = (_Float16)((hnew - (float)hh) * LO_SCALE);
            }
            // C1: residual-MLP hidden for step t (tid<256, one unit each)
            if (tid < MM*64) {
                const float xp0 = xprev[m1*2], xp1 = xprev[m1*2+1];
                const float v0 = vb[m1*2], v1 = vb[m1*2+1];
                float h0 = ab + a0*xp0 + a1*xp1 + a2*v0 + a3*v1;
                hid[m1*64 + k1] = fmaxf(h0, 0.0f);
            }
        }
    }
}

extern "C" void kernel_launch(void* const* d_in, const int* in_sizes, int n_in,
                              void* d_out, int out_size, void* d_ws, size_t ws_size,
                              hipStream_t stream) {
    pig_kernel<<<dim3(NBLK), dim3(BLK), 0, stream>>>(
        (const float*)d_in[0],  (const float*)d_in[1],  (const float*)d_in[2],
        (const float*)d_in[3],  (const float*)d_in[4],  (const float*)d_in[5],
        (const float*)d_in[6],  (const float*)d_in[7],  (const float*)d_in[8],
        (const float*)d_in[9],  (const float*)d_in[10], (const float*)d_in[11],
        (float*)d_out);
}

// Round 5
// 589.693 us; speedup vs baseline: 1.9595x; 1.3250x over previous
//
#include <hip/hip_runtime.h>
#include <stdint.h>

#define BB 1024
#define SS 512
#define HH 128
#define MM 4            // batch rows per block
#define BLK 512
#define NBLK (BB / MM)  // 256 blocks -> 1 per CU
#define HPS 136         // hpack row stride in f16 (272B rows, 16B-aligned)

typedef float f32x4 __attribute__((ext_vector_type(4)));
typedef _Float16 f16x8 __attribute__((ext_vector_type(8)));

#define LO_SCALE 2048.0f
#define LO_INV   (1.0f / 2048.0f)
#define LO_INV2  (LO_INV * LO_INV)

__device__ __forceinline__ float sigf(float x) { return 1.0f / (1.0f + __expf(-x)); }
__device__ __forceinline__ float tanh_fast(float x) { return 2.0f / (1.0f + __expf(-2.0f * x)) - 1.0f; }

__global__ __launch_bounds__(BLK, 2) void pig_kernel(
    const float* __restrict__ x0, const float* __restrict__ v_seq,
    const float* __restrict__ W_ih, const float* __restrict__ W_hh,
    const float* __restrict__ b_ih, const float* __restrict__ b_hh,
    const float* __restrict__ W_out, const float* __restrict__ b_out,
    const float* __restrict__ W_r1, const float* __restrict__ b_r1,
    const float* __restrict__ W_r2, const float* __restrict__ b_r2,
    float* __restrict__ out)
{
    // hpack row r = 4m+p: p=0 -> h_hi[m], p=1 -> h_lo[m]*2048, p=2,3 -> zero (never written)
    __shared__ __align__(16) _Float16 hpack[2][16 * HPS];
    __shared__ __align__(16) float    hid[MM * 64];     // residual-MLP hidden (wave0 only)
    __shared__ float xprev[MM * 2];
    __shared__ float vbuf[2][MM * 2];

    const int tid  = threadIdx.x;
    const int wave = tid >> 6;
    const int lane = tid & 63;
    const int quad = lane >> 4;
    const int col  = lane & 15;
    const int row0 = blockIdx.x * MM;
    const int j    = wave * 16 + col;   // this lane's hidden index (all quads same j)

    // ---- W_hh B-fragments: wave w's tiles are gates nt*128 + w*16 .. +15 ----
    // B[k][n]: lane holds n = col (gate-in-tile), k = kk*32 + quad*8 + i
    f16x8 whi[3][4], wlo[3][4];
#pragma unroll
    for (int nt = 0; nt < 3; ++nt) {
        const int g = nt * HH + j;
#pragma unroll
        for (int kk = 0; kk < 4; ++kk) {
            const float* p = W_hh + g * HH + kk * 32 + quad * 8;
            f16x8 fh, fl;
#pragma unroll
            for (int i = 0; i < 8; ++i) {
                float w = p[i];
                _Float16 h = (_Float16)w;
                fh[i] = h;
                fl[i] = (_Float16)((w - (float)h) * LO_SCALE);
            }
            whi[nt][kk] = fh;
            wlo[nt][kk] = fl;
        }
    }

    // ---- gate-math per-lane constants (hidden index j, batch row m=quad) ----
    const float wr0 = W_ih[j*2],        wr1 = W_ih[j*2+1];
    const float wz0 = W_ih[(HH+j)*2],   wz1 = W_ih[(HH+j)*2+1];
    const float wn0 = W_ih[(2*HH+j)*2], wn1 = W_ih[(2*HH+j)*2+1];
    const float br  = b_ih[j]      + b_hh[j];
    const float bz  = b_ih[HH+j]   + b_hh[HH+j];
    const float bni = b_ih[2*HH+j];
    const float bnh = b_hh[2*HH+j];

    // ---- wave0 C2 constants: group g8 = lane>>3 -> (m,o); lane-in-group k8 handles 16 h-elems ----
    const int g8 = lane >> 3;
    const int mO = g8 >> 1, oO = g8 & 1, k8 = lane & 7;
    float wo[16], w2[8];
#pragma unroll
    for (int i = 0; i < 16; ++i) wo[i] = W_out[oO*HH + k8*16 + i];
#pragma unroll
    for (int i = 0; i < 8; ++i)  w2[i] = W_r2[oO*64 + k8*8 + i];
    const float bo = b_out[oO], b2 = b_r2[oO];

    // ---- wave0 C1 constants: lane -> (m1, 4 hidden units) ----
    const int m1 = lane >> 4;
    const int kb = (lane & 15) * 4;
    float a[4][4], ab[4];
#pragma unroll
    for (int u = 0; u < 4; ++u) {
#pragma unroll
        for (int q = 0; q < 4; ++q) a[u][q] = W_r1[(kb+u)*4 + q];
        ab[u] = b_r1[kb+u];
    }

    // ---- init ----
    for (int idx = tid; idx < 2 * 16 * HPS; idx += BLK) ((_Float16*)hpack)[idx] = (_Float16)0.0f;
    if (tid < MM*2) {
        xprev[tid]   = x0[(size_t)(row0 + (tid >> 1)) * 2 + (tid & 1)];
        vbuf[0][tid] = v_seq[((size_t)(row0 + (tid >> 1)) * SS) * 2 + (tid & 1)];
    }
    __syncthreads();

    float hold = 0.0f;   // h[quad][j] in fp32, the trajectory-critical state
    for (int t = 0; t <= SS; ++t) {
        const int cur = t & 1, nxt = cur ^ 1;
        float vpre = 0.0f;
        if (wave == 0 && lane < MM*2 && (t + 1) < SS)
            vpre = v_seq[((size_t)(row0 + (lane >> 1)) * SS + (t + 1)) * 2 + (lane & 1)];

        if (t < SS) {
            f32x4 aH0 = {0,0,0,0}, aH1 = {0,0,0,0}, aH2 = {0,0,0,0};
            f32x4 aL0 = {0,0,0,0}, aL1 = {0,0,0,0}, aL2 = {0,0,0,0};
#pragma unroll
            for (int kk = 0; kk < 4; ++kk) {
                f16x8 af = *(const f16x8*)&hpack[cur][col * HPS + kk * 32 + quad * 8];
                aH0 = __builtin_amdgcn_mfma_f32_16x16x32_f16(af, whi[0][kk], aH0, 0, 0, 0);
                aH1 = __builtin_amdgcn_mfma_f32_16x16x32_f16(af, whi[1][kk], aH1, 0, 0, 0);
                aH2 = __builtin_amdgcn_mfma_f32_16x16x32_f16(af, whi[2][kk], aH2, 0, 0, 0);
                aL0 = __builtin_amdgcn_mfma_f32_16x16x32_f16(af, wlo[0][kk], aL0, 0, 0, 0);
                aL1 = __builtin_amdgcn_mfma_f32_16x16x32_f16(af, wlo[1][kk], aL1, 0, 0, 0);
                aL2 = __builtin_amdgcn_mfma_f32_16x16x32_f16(af, wlo[2][kk], aL2, 0, 0, 0);
            }
            // lane (quad,col): acc[0] = row 4*quad (hi part), acc[1] = row 4*quad+1 (lo part)
            const float gh0 = aH0[0] + (aH0[1] + aL0[0]) * LO_INV + aL0[1] * LO_INV2;
            const float gh1 = aH1[0] + (aH1[1] + aL1[0]) * LO_INV + aL1[1] * LO_INV2;
            const float gh2 = aH2[0] + (aH2[1] + aL2[0]) * LO_INV + aL2[1] * LO_INV2;

            const float v0 = vbuf[cur][quad*2], v1 = vbuf[cur][quad*2+1];
            const float r = sigf(gh0 + v0*wr0 + v1*wr1 + br);
            const float z = sigf(gh1 + v0*wz0 + v1*wz1 + bz);
            const float n = tanh_fast(v0*wn0 + v1*wn1 + bni + r * (gh2 + bnh));
            hold = n + z * (hold - n);

            _Float16 hh = (_Float16)hold;
            hpack[nxt][(4*quad)     * HPS + j] = hh;
            hpack[nxt][(4*quad + 1) * HPS + j] = (_Float16)((hold - (float)hh) * LO_SCALE);
        }

        if (wave == 0) {
            if (t > 0) {   // C2: outputs for step t-1; h(t-1) is in hpack[cur]
                const int tt = t - 1;
                const f16x8 hi0 = *(const f16x8*)&hpack[cur][(4*mO)   * HPS + k8*16];
                const f16x8 hi1 = *(const f16x8*)&hpack[cur][(4*mO)   * HPS + k8*16 + 8];
                const f16x8 lo0 = *(const f16x8*)&hpack[cur][(4*mO+1) * HPS + k8*16];
                const f16x8 lo1 = *(const f16x8*)&hpack[cur][(4*mO+1) * HPS + k8*16 + 8];
                float xps = 0.0f;
#pragma unroll
                for (int i = 0; i < 8; ++i) {
                    xps += ((float)hi0[i] + (float)lo0[i] * LO_INV) * wo[i];
                    xps += ((float)hi1[i] + (float)lo1[i] * LO_INV) * wo[8+i];
                }
                float rss = 0.0f;
#pragma unroll
                for (int i = 0; i < 8; ++i) rss += hid[mO*64 + k8*8 + i] * w2[i];
#pragma unroll
                for (int s = 4; s >= 1; s >>= 1) {
                    xps += __shfl_xor(xps, s, 64);
                    rss += __shfl_xor(rss, s, 64);
                }
                if (k8 == 0) {
                    const float xpred = xps + bo;
                    const float resid = rss + b2;
                    const float xpv   = xprev[mO*2 + oO];
                    const float vv    = vbuf[nxt][mO*2 + oO];   // slot (t-1)&1 == nxt: still holds v(t-1)
                    const float viol  = xpred - (xpv + vv + resid);
                    const size_t base = ((size_t)(row0 + mO) * SS + tt) * 2 + oO;
                    out[base] = xpred;
                    out[(size_t)BB * SS * 2 + base] = viol;
                    xprev[mO*2 + oO] = xpred;   // becomes x_prev for step t
                }
            }
            if (t < SS) {   // C1: hid(t) from xprev (= x_pred(t-1)) and v(t)
                const float xp0 = xprev[m1*2], xp1 = xprev[m1*2+1];
                const float v0 = vbuf[cur][m1*2], v1 = vbuf[cur][m1*2+1];
#pragma unroll
                for (int u = 0; u < 4; ++u) {
                    float h = ab[u] + a[u][0]*xp0 + a[u][1]*xp1 + a[u][2]*v0 + a[u][3]*v1;
                    hid[m1*64 + kb + u] = fmaxf(h, 0.0f);
                }
                if (lane < MM*2 && (t + 1) < SS) vbuf[nxt][lane] = vpre;  // after C2's vv read
            }
        }
        __syncthreads();   // the single per-step barrier
    }
}

extern "C" void kernel_launch(void* const* d_in, const int* in_sizes, int n_in,
                              void* d_out, int out_size, void* d_ws, size_t ws_size,
                              hipStream_t stream) {
    pig_kernel<<<dim3(NBLK), dim3(BLK), 0, stream>>>(
        (const float*)d_in[0],  (const float*)d_in[1],  (const float*)d_in[2],
        (const float*)d_in[3],  (const float*)d_in[4],  (const float*)d_in[5],
        (const float*)d_in[6],  (const float*)d_in[7],  (const float*)d_in[8],
        (const float*)d_in[9],  (const float*)d_in[10], (const float*)d_in[11],
        (float*)d_out);
}